// Round 6
// baseline (1170.827 us; speedup 1.0000x reference)
//
#include <hip/hip_runtime.h>

#define N_NODES 100000
#define N_EDGES 1600000
#define IN_F 512
#define HID 64
#define N_CLS 32
#define NBKT2 391      // 256-node buckets: ceil(100000/256)
#define EBLK 8192      // edges per passA/coarse-hist block
#define NBLKA ((N_EDGES + EBLK - 1) / EBLK)   // 196

typedef __attribute__((ext_vector_type(8))) short short8;
typedef __attribute__((ext_vector_type(4))) float f32x4;

__device__ __forceinline__ unsigned short f2bf(float f) {
  unsigned int u = __float_as_uint(f);
  u += 0x7FFFu + ((u >> 16) & 1u);
  return (unsigned short)(u >> 16);
}
__device__ __forceinline__ float bf2f(unsigned int s) {
  return __uint_as_float(s << 16);
}

// ---------- coarse histogram over 391 buckets (LDS-staged) ----------
__global__ __launch_bounds__(256) void coarse_hist_k(const int* __restrict__ ei,
                                                     int* __restrict__ bcnt) {
  __shared__ int lh[NBKT2];
  int tid = threadIdx.x;
  for (int b = tid; b < NBKT2; b += 256) lh[b] = 0;
  __syncthreads();
  int e0 = blockIdx.x * EBLK;
  int e1 = min(e0 + EBLK, N_EDGES);
  for (int e = e0 + tid; e < e1; e += 256)
    atomicAdd(&lh[ei[N_EDGES + e] >> 8], 1);
  __syncthreads();
  for (int b = tid; b < NBKT2; b += 256) {
    int c = lh[b];
    if (c) atomicAdd(&bcnt[b], c);
  }
}

// ---------- single-block scan of 391 bucket counts ----------
__global__ __launch_bounds__(512) void coarse_scan_k(const int* __restrict__ bcnt,
                                                     int* __restrict__ bbase,
                                                     int* __restrict__ bcur) {
  __shared__ int sc[512];
  int tid = threadIdx.x;
  int v = (tid < NBKT2) ? bcnt[tid] : 0;
  sc[tid] = v;
  __syncthreads();
  for (int off = 1; off < 512; off <<= 1) {
    int t = (tid >= off) ? sc[tid - off] : 0;
    __syncthreads();
    sc[tid] += t;
    __syncthreads();
  }
  int incl = sc[tid];
  int excl = incl - v;
  if (tid < NBKT2) { bbase[tid] = excl; bcur[tid] = excl; }
  if (tid == NBKT2 - 1) bbase[NBKT2] = incl;   // == N_EDGES
}

// ---------- pass A: block-private run reservation into 256-node buckets ----------
__global__ __launch_bounds__(256) void passA_k(const int* __restrict__ ei,
                                               int* __restrict__ bcur,
                                               unsigned* __restrict__ tmp) {
  __shared__ int lhist[NBKT2];
  __shared__ int gcur[NBKT2];
  int tid = threadIdx.x;
  int e0 = blockIdx.x * EBLK;
  int e1 = min(e0 + EBLK, N_EDGES);
  for (int b = tid; b < NBKT2; b += 256) lhist[b] = 0;
  __syncthreads();
  for (int e = e0 + tid; e < e1; e += 256) {
    int d = ei[N_EDGES + e];
    atomicAdd(&lhist[d >> 8], 1);
  }
  __syncthreads();
  for (int b = tid; b < NBKT2; b += 256) {
    int c = lhist[b];
    gcur[b] = c ? atomicAdd(&bcur[b], c) : 0;
  }
  __syncthreads();
  for (int e = e0 + tid; e < e1; e += 256) {
    int s = ei[e], d = ei[N_EDGES + e];
    int p = atomicAdd(&gcur[d >> 8], 1);
    tmp[p] = ((unsigned)s << 8) | (unsigned)(d & 255);
  }
}

// ---------- per-bucket degree -> dinv ----------
__global__ __launch_bounds__(256) void dinv_k(const unsigned* __restrict__ tmp,
                                              const int* __restrict__ bbase,
                                              float* __restrict__ dinv) {
  __shared__ int cnt[256];
  int b = blockIdx.x, tid = threadIdx.x;
  cnt[tid] = 0;
  __syncthreads();
  int base = bbase[b], end = bbase[b + 1];
  for (int i = base + tid; i < end; i += 256)
    atomicAdd(&cnt[tmp[i] & 255u], 1);
  __syncthreads();
  int n = (b << 8) + tid;
  if (n < N_NODES) dinv[n] = rsqrtf((float)(cnt[tid] + 1));
}

// ---------- W1 transpose to bf16 ----------
__global__ __launch_bounds__(256) void w1t_k(const float* __restrict__ W1,
                                             unsigned short* __restrict__ W1t) {
  int i = blockIdx.x * 256 + threadIdx.x;
  if (i < IN_F * HID) {
    int n = i >> 9, k = i & 511;
    W1t[i] = f2bf(W1[(size_t)k * HID + n]);
  }
}

// ---------- GEMM1 (MFMA bf16): h0s = dinv * (x @ W1), bf16 ----------
__global__ __launch_bounds__(256) void gemm1_mfma_k(const float* __restrict__ x,
                                                    const unsigned short* __restrict__ W1t,
                                                    const float* __restrict__ dinv,
                                                    unsigned short* __restrict__ h0s) {
  __shared__ __align__(16) char As[64 * 128];
  __shared__ __align__(16) char Ws[64 * 128];
  int tid = threadIdx.x;
  int wave = tid >> 6, lane = tid & 63;
  int row0 = blockIdx.x * 64;
  f32x4 acc[4] = {{0.f,0.f,0.f,0.f},{0.f,0.f,0.f,0.f},{0.f,0.f,0.f,0.f},{0.f,0.f,0.f,0.f}};

  int l15 = lane & 15, lhi = lane >> 4;
  int rA = (wave << 4) + l15;

  for (int k0 = 0; k0 < IN_F; k0 += 64) {
    #pragma unroll
    for (int i = 0; i < 4; ++i) {
      int f = tid + i * 256;
      int r = f >> 4, c4 = (f & 15) << 2;
      float4 v = make_float4(0.f, 0.f, 0.f, 0.f);
      int gr = row0 + r;
      if (gr < N_NODES) v = *(const float4*)(x + (size_t)gr * IN_F + k0 + c4);
      ushort4 u;
      u.x = f2bf(v.x); u.y = f2bf(v.y); u.z = f2bf(v.z); u.w = f2bf(v.w);
      int byte = r * 128 + (c4 << 1);
      byte ^= (r & 7) << 4;
      *(ushort4*)(As + byte) = u;
    }
    #pragma unroll
    for (int i = 0; i < 2; ++i) {
      int f = tid + i * 256;
      int n = f >> 3, k8 = (f & 7) << 3;
      uint4 v = *(const uint4*)(W1t + (size_t)n * IN_F + k0 + k8);
      int byte = n * 128 + (k8 << 1);
      byte ^= (n & 7) << 4;
      *(uint4*)(Ws + byte) = v;
    }
    __syncthreads();
    #pragma unroll
    for (int ks = 0; ks < 64; ks += 32) {
      int kk = ks + (lhi << 3);
      int ba = rA * 128 + (kk << 1); ba ^= (rA & 7) << 4;
      short8 a = *(const short8*)(As + ba);
      #pragma unroll
      for (int j = 0; j < 4; ++j) {
        int nB = (j << 4) + l15;
        int bb = nB * 128 + (kk << 1); bb ^= (nB & 7) << 4;
        short8 bv = *(const short8*)(Ws + bb);
        acc[j] = __builtin_amdgcn_mfma_f32_16x16x32_bf16(a, bv, acc[j], 0, 0, 0);
      }
    }
    __syncthreads();
  }
  int rbase = row0 + (wave << 4) + (lhi << 2);
  #pragma unroll
  for (int r = 0; r < 4; ++r) {
    int gr = rbase + r;
    if (gr < N_NODES) {
      float dn = dinv[gr];
      #pragma unroll
      for (int j = 0; j < 4; ++j)
        h0s[(size_t)gr * HID + (j << 4) + l15] = f2bf(dn * acc[j][r]);
    }
  }
}

// ---------- agg1 (LDS scatter): one block per bucket ----------
// acc[dst_low][feat] += h0s[src][feat]; out = relu(dinv*(acc+self)+b1)
__global__ __launch_bounds__(512) void agg1_lds_k(const unsigned* __restrict__ h0u,
                                                  const unsigned* __restrict__ tmp,
                                                  const int* __restrict__ bbase,
                                                  const float* __restrict__ dinv,
                                                  const float* __restrict__ b1,
                                                  float* __restrict__ out) {
  __shared__ float acc[256][65];   // stride 65 spreads banks across dst rows
  int b = blockIdx.x, tid = threadIdx.x;
  int n0 = b << 8;
  int nn = min(256, N_NODES - n0);
  float* af = &acc[0][0];
  for (int i = tid; i < 256 * 65; i += 512) af[i] = 0.f;
  __syncthreads();
  int base = bbase[b], end = bbase[b + 1];
  int hw = tid >> 5, ln = tid & 31;     // 16 half-waves, 32 lanes each
  int i = base + hw;
  for (; i + 48 < end; i += 64) {       // 4 edges per half-wave per iter
    unsigned p0 = tmp[i], p1 = tmp[i + 16], p2 = tmp[i + 32], p3 = tmp[i + 48];
    unsigned u0 = h0u[(size_t)(p0 >> 8) * 32 + ln];
    unsigned u1 = h0u[(size_t)(p1 >> 8) * 32 + ln];
    unsigned u2 = h0u[(size_t)(p2 >> 8) * 32 + ln];
    unsigned u3 = h0u[(size_t)(p3 >> 8) * 32 + ln];
    atomicAdd(&acc[p0 & 255u][ln * 2],     bf2f(u0 & 0xffffu));
    atomicAdd(&acc[p0 & 255u][ln * 2 + 1], bf2f(u0 >> 16));
    atomicAdd(&acc[p1 & 255u][ln * 2],     bf2f(u1 & 0xffffu));
    atomicAdd(&acc[p1 & 255u][ln * 2 + 1], bf2f(u1 >> 16));
    atomicAdd(&acc[p2 & 255u][ln * 2],     bf2f(u2 & 0xffffu));
    atomicAdd(&acc[p2 & 255u][ln * 2 + 1], bf2f(u2 >> 16));
    atomicAdd(&acc[p3 & 255u][ln * 2],     bf2f(u3 & 0xffffu));
    atomicAdd(&acc[p3 & 255u][ln * 2 + 1], bf2f(u3 >> 16));
  }
  for (; i < end; i += 16) {
    unsigned p = tmp[i];
    unsigned u = h0u[(size_t)(p >> 8) * 32 + ln];
    atomicAdd(&acc[p & 255u][ln * 2],     bf2f(u & 0xffffu));
    atomicAdd(&acc[p & 255u][ln * 2 + 1], bf2f(u >> 16));
  }
  __syncthreads();
  for (int j = tid; j < nn * 16; j += 512) {
    int node = j >> 4, c4 = (j & 15) << 2;
    int gn = n0 + node;
    float dn = dinv[gn];
    unsigned s0 = h0u[(size_t)gn * 32 + (c4 >> 1)];
    unsigned s1 = h0u[(size_t)gn * 32 + (c4 >> 1) + 1];
    float4 bv = *(const float4*)(b1 + c4);
    float4 st;
    st.x = fmaxf(dn * (acc[node][c4]     + bf2f(s0 & 0xffffu)) + bv.x, 0.f);
    st.y = fmaxf(dn * (acc[node][c4 + 1] + bf2f(s0 >> 16))     + bv.y, 0.f);
    st.z = fmaxf(dn * (acc[node][c4 + 2] + bf2f(s1 & 0xffffu)) + bv.z, 0.f);
    st.w = fmaxf(dn * (acc[node][c4 + 3] + bf2f(s1 >> 16))     + bv.w, 0.f);
    *(float4*)(out + (size_t)gn * HID + c4) = st;
  }
}

// ---------- GEMM2: h2b = bf16(dinv * (h @ W2)), 32 nodes/block ----------
__global__ __launch_bounds__(256) void gemm2_k(const float* __restrict__ h,
                                               const float* __restrict__ W2,
                                               const float* __restrict__ dinv,
                                               unsigned short* __restrict__ h2b) {
  __shared__ float w2s[HID * N_CLS];
  __shared__ float hs[32][HID];
  int tid = threadIdx.x;
  for (int i = tid; i < HID * N_CLS; i += 256) w2s[i] = W2[i];
  int node0 = blockIdx.x * 32;
  for (int i = tid; i < 32 * HID / 4; i += 256) {
    int r = i >> 4, c4 = (i & 15) << 2;
    int g = node0 + r;
    float4 v = make_float4(0.f, 0.f, 0.f, 0.f);
    if (g < N_NODES) v = *(const float4*)(h + (size_t)g * HID + c4);
    *(float4*)&hs[r][c4] = v;
  }
  __syncthreads();
  int cls = tid & 31, nl = tid >> 5;
  float acc[4] = {0.f, 0.f, 0.f, 0.f};
  #pragma unroll
  for (int k = 0; k < HID; ++k) {
    float w = w2s[k * N_CLS + cls];
    #pragma unroll
    for (int j = 0; j < 4; ++j) acc[j] += hs[nl * 4 + j][k] * w;
  }
  #pragma unroll
  for (int j = 0; j < 4; ++j) {
    int g = node0 + nl * 4 + j;
    if (g < N_NODES) h2b[(size_t)g * N_CLS + cls] = f2bf(dinv[g] * acc[j]);
  }
}

// ---------- agg2 (LDS scatter): one block per bucket ----------
__global__ __launch_bounds__(512) void agg2_lds_k(const unsigned* __restrict__ h2u,
                                                  const unsigned* __restrict__ tmp,
                                                  const int* __restrict__ bbase,
                                                  const float* __restrict__ dinv,
                                                  const float* __restrict__ b2,
                                                  float* __restrict__ out) {
  __shared__ float acc[256][33];
  int b = blockIdx.x, tid = threadIdx.x;
  int n0 = b << 8;
  int nn = min(256, N_NODES - n0);
  float* af = &acc[0][0];
  for (int i = tid; i < 256 * 33; i += 512) af[i] = 0.f;
  __syncthreads();
  int base = bbase[b], end = bbase[b + 1];
  int grp = tid >> 4, ln = tid & 15;    // 32 groups, 16 lanes each
  int i = base + grp;
  for (; i + 96 < end; i += 128) {      // 4 edges per group per iter
    unsigned p0 = tmp[i], p1 = tmp[i + 32], p2 = tmp[i + 64], p3 = tmp[i + 96];
    unsigned u0 = h2u[(size_t)(p0 >> 8) * 16 + ln];
    unsigned u1 = h2u[(size_t)(p1 >> 8) * 16 + ln];
    unsigned u2 = h2u[(size_t)(p2 >> 8) * 16 + ln];
    unsigned u3 = h2u[(size_t)(p3 >> 8) * 16 + ln];
    atomicAdd(&acc[p0 & 255u][ln * 2],     bf2f(u0 & 0xffffu));
    atomicAdd(&acc[p0 & 255u][ln * 2 + 1], bf2f(u0 >> 16));
    atomicAdd(&acc[p1 & 255u][ln * 2],     bf2f(u1 & 0xffffu));
    atomicAdd(&acc[p1 & 255u][ln * 2 + 1], bf2f(u1 >> 16));
    atomicAdd(&acc[p2 & 255u][ln * 2],     bf2f(u2 & 0xffffu));
    atomicAdd(&acc[p2 & 255u][ln * 2 + 1], bf2f(u2 >> 16));
    atomicAdd(&acc[p3 & 255u][ln * 2],     bf2f(u3 & 0xffffu));
    atomicAdd(&acc[p3 & 255u][ln * 2 + 1], bf2f(u3 >> 16));
  }
  for (; i < end; i += 32) {
    unsigned p = tmp[i];
    unsigned u = h2u[(size_t)(p >> 8) * 16 + ln];
    atomicAdd(&acc[p & 255u][ln * 2],     bf2f(u & 0xffffu));
    atomicAdd(&acc[p & 255u][ln * 2 + 1], bf2f(u >> 16));
  }
  __syncthreads();
  for (int j = tid; j < nn * 8; j += 512) {
    int node = j >> 3, c4 = (j & 7) << 2;
    int gn = n0 + node;
    float dn = dinv[gn];
    unsigned s0 = h2u[(size_t)gn * 16 + (c4 >> 1)];
    unsigned s1 = h2u[(size_t)gn * 16 + (c4 >> 1) + 1];
    float4 bv = *(const float4*)(b2 + c4);
    float4 st;
    st.x = dn * (acc[node][c4]     + bf2f(s0 & 0xffffu)) + bv.x;
    st.y = dn * (acc[node][c4 + 1] + bf2f(s0 >> 16))     + bv.y;
    st.z = dn * (acc[node][c4 + 2] + bf2f(s1 & 0xffffu)) + bv.z;
    st.w = dn * (acc[node][c4 + 3] + bf2f(s1 >> 16))     + bv.w;
    *(float4*)(out + (size_t)gn * N_CLS + c4) = st;
  }
}

extern "C" void kernel_launch(void* const* d_in, const int* in_sizes, int n_in,
                              void* d_out, int out_size, void* d_ws, size_t ws_size,
                              hipStream_t stream) {
  const float* x  = (const float*)d_in[0];
  const int*   ei = (const int*)d_in[1];
  const float* W1 = (const float*)d_in[2];
  const float* b1 = (const float*)d_in[3];
  const float* W2 = (const float*)d_in[4];
  const float* b2 = (const float*)d_in[5];
  float* out_h = (float*)d_out;
  float* out_z = out_h + (size_t)N_NODES * HID;

  char* ws = (char*)d_ws;
  int* bcnt           = (int*)(ws + 0);                       // 1.6 KB
  int* bbase          = (int*)(ws + (4 << 10));               // 1.6 KB
  int* bcur           = (int*)(ws + (8 << 10));               // 1.6 KB
  float* dinv         = (float*)(ws + (16 << 10));            // 400 KB
  unsigned short* W1t = (unsigned short*)(ws + (432 << 10));  // 64 KB
  unsigned* tmp       = (unsigned*)(ws + (512 << 10));        // 6.4 MB
  unsigned short* h0s = (unsigned short*)(ws + (7ull << 20)); // 12.8 MB
  unsigned short* h2b = (unsigned short*)(ws + (20ull << 20));// 6.4 MB

  hipMemsetAsync(bcnt, 0, NBKT2 * sizeof(int), stream);
  w1t_k<<<(IN_F * HID + 255) / 256, 256, 0, stream>>>(W1, W1t);
  coarse_hist_k<<<NBLKA, 256, 0, stream>>>(ei, bcnt);
  coarse_scan_k<<<1, 512, 0, stream>>>(bcnt, bbase, bcur);
  passA_k<<<NBLKA, 256, 0, stream>>>(ei, bcur, tmp);
  dinv_k<<<NBKT2, 256, 0, stream>>>(tmp, bbase, dinv);
  gemm1_mfma_k<<<(N_NODES + 63) / 64, 256, 0, stream>>>(x, W1t, dinv, h0s);
  agg1_lds_k<<<NBKT2, 512, 0, stream>>>((const unsigned*)h0s, tmp, bbase, dinv, b1, out_h);
  gemm2_k<<<(N_NODES + 31) / 32, 256, 0, stream>>>(out_h, W2, dinv, h2b);
  agg2_lds_k<<<NBKT2, 512, 0, stream>>>((const unsigned*)h2b, tmp, bbase, dinv, b2, out_z);
}

// Round 7
// 368.680 us; speedup vs baseline: 3.1757x; 3.1757x over previous
//
#include <hip/hip_runtime.h>

#define N_NODES 100000
#define N_EDGES 1600000
#define IN_F 512
#define HID 64
#define N_CLS 32
#define NBKT2 391      // 256-node buckets: ceil(100000/256)
#define EBLK 8192      // edges per passA/coarse-hist block
#define NBLKA ((N_EDGES + EBLK - 1) / EBLK)   // 196

typedef __attribute__((ext_vector_type(8))) short short8;
typedef __attribute__((ext_vector_type(4))) float f32x4;

__device__ __forceinline__ unsigned short f2bf(float f) {
  unsigned int u = __float_as_uint(f);
  u += 0x7FFFu + ((u >> 16) & 1u);
  return (unsigned short)(u >> 16);
}
__device__ __forceinline__ float bf2f(unsigned int s) {
  return __uint_as_float(s << 16);
}

// ---------- coarse histogram over 391 buckets (LDS-staged) ----------
__global__ __launch_bounds__(256) void coarse_hist_k(const int* __restrict__ ei,
                                                     int* __restrict__ bcnt) {
  __shared__ int lh[NBKT2];
  int tid = threadIdx.x;
  for (int b = tid; b < NBKT2; b += 256) lh[b] = 0;
  __syncthreads();
  int e0 = blockIdx.x * EBLK;
  int e1 = min(e0 + EBLK, N_EDGES);
  for (int e = e0 + tid; e < e1; e += 256)
    atomicAdd(&lh[ei[N_EDGES + e] >> 8], 1);
  __syncthreads();
  for (int b = tid; b < NBKT2; b += 256) {
    int c = lh[b];
    if (c) atomicAdd(&bcnt[b], c);
  }
}

// ---------- single-block scan of 391 bucket counts ----------
__global__ __launch_bounds__(512) void coarse_scan_k(const int* __restrict__ bcnt,
                                                     int* __restrict__ bbase,
                                                     int* __restrict__ bcur) {
  __shared__ int sc[512];
  int tid = threadIdx.x;
  int v = (tid < NBKT2) ? bcnt[tid] : 0;
  sc[tid] = v;
  __syncthreads();
  for (int off = 1; off < 512; off <<= 1) {
    int t = (tid >= off) ? sc[tid - off] : 0;
    __syncthreads();
    sc[tid] += t;
    __syncthreads();
  }
  int incl = sc[tid];
  int excl = incl - v;
  if (tid < NBKT2) { bbase[tid] = excl; bcur[tid] = excl; }
  if (tid == NBKT2 - 1) bbase[NBKT2] = incl;   // == N_EDGES
}

// ---------- pass A: block-private run reservation into 256-node buckets ----------
__global__ __launch_bounds__(256) void passA_k(const int* __restrict__ ei,
                                               int* __restrict__ bcur,
                                               unsigned* __restrict__ tmp) {
  __shared__ int lhist[NBKT2];
  __shared__ int gcur[NBKT2];
  int tid = threadIdx.x;
  int e0 = blockIdx.x * EBLK;
  int e1 = min(e0 + EBLK, N_EDGES);
  for (int b = tid; b < NBKT2; b += 256) lhist[b] = 0;
  __syncthreads();
  for (int e = e0 + tid; e < e1; e += 256) {
    int d = ei[N_EDGES + e];
    atomicAdd(&lhist[d >> 8], 1);
  }
  __syncthreads();
  for (int b = tid; b < NBKT2; b += 256) {
    int c = lhist[b];
    gcur[b] = c ? atomicAdd(&bcur[b], c) : 0;
  }
  __syncthreads();
  for (int e = e0 + tid; e < e1; e += 256) {
    int s = ei[e], d = ei[N_EDGES + e];
    int p = atomicAdd(&gcur[d >> 8], 1);
    tmp[p] = ((unsigned)s << 8) | (unsigned)(d & 255);
  }
}

// ---------- pass B: per-bucket node hist + scan + rowptr/dinv + exact placement ----------
__global__ __launch_bounds__(256) void passB_k(const unsigned* __restrict__ tmp,
                                               const int* __restrict__ bbase,
                                               int* __restrict__ rowptr,
                                               float* __restrict__ dinv,
                                               int* __restrict__ srcs) {
  __shared__ int sc[256];
  __shared__ int cur[256];
  int b = blockIdx.x, tid = threadIdx.x;
  int n0 = b << 8;
  int n1 = min(n0 + 256, N_NODES);
  int base = bbase[b], end = bbase[b + 1];
  sc[tid] = 0;
  __syncthreads();
  for (int i = base + tid; i < end; i += 256)
    atomicAdd(&sc[tmp[i] & 255u], 1);
  __syncthreads();
  int myc = sc[tid];
  for (int off = 1; off < 256; off <<= 1) {
    int t = (tid >= off) ? sc[tid - off] : 0;
    __syncthreads();
    sc[tid] += t;
    __syncthreads();
  }
  int incl = sc[tid];
  int excl = incl - myc;
  if (n0 + tid < n1) {
    rowptr[n0 + tid + 1] = base + incl;
    dinv[n0 + tid] = rsqrtf((float)(myc + 1));
  }
  if (b == 0 && tid == 0) rowptr[0] = 0;
  cur[tid] = base + excl;
  __syncthreads();
  for (int i = base + tid; i < end; i += 256) {
    unsigned v = tmp[i];
    int p = atomicAdd(&cur[v & 255u], 1);
    srcs[p] = (int)(v >> 8);
  }
}

// ---------- W1 transpose to bf16 ----------
__global__ __launch_bounds__(256) void w1t_k(const float* __restrict__ W1,
                                             unsigned short* __restrict__ W1t) {
  int i = blockIdx.x * 256 + threadIdx.x;
  if (i < IN_F * HID) {
    int n = i >> 9, k = i & 511;
    W1t[i] = f2bf(W1[(size_t)k * HID + n]);
  }
}

// ---------- GEMM1 (MFMA bf16): h0q[j][node][16] = dinv*(x@W1) quarter-split ----------
__global__ __launch_bounds__(256) void gemm1_mfma_k(const float* __restrict__ x,
                                                    const unsigned short* __restrict__ W1t,
                                                    const float* __restrict__ dinv,
                                                    unsigned short* __restrict__ h0q) {
  __shared__ __align__(16) char As[64 * 128];
  __shared__ __align__(16) char Ws[64 * 128];
  int tid = threadIdx.x;
  int wave = tid >> 6, lane = tid & 63;
  int row0 = blockIdx.x * 64;
  f32x4 acc[4] = {{0.f,0.f,0.f,0.f},{0.f,0.f,0.f,0.f},{0.f,0.f,0.f,0.f},{0.f,0.f,0.f,0.f}};

  int l15 = lane & 15, lhi = lane >> 4;
  int rA = (wave << 4) + l15;

  for (int k0 = 0; k0 < IN_F; k0 += 64) {
    #pragma unroll
    for (int i = 0; i < 4; ++i) {
      int f = tid + i * 256;
      int r = f >> 4, c4 = (f & 15) << 2;
      float4 v = make_float4(0.f, 0.f, 0.f, 0.f);
      int gr = row0 + r;
      if (gr < N_NODES) v = *(const float4*)(x + (size_t)gr * IN_F + k0 + c4);
      ushort4 u;
      u.x = f2bf(v.x); u.y = f2bf(v.y); u.z = f2bf(v.z); u.w = f2bf(v.w);
      int byte = r * 128 + (c4 << 1);
      byte ^= (r & 7) << 4;
      *(ushort4*)(As + byte) = u;
    }
    #pragma unroll
    for (int i = 0; i < 2; ++i) {
      int f = tid + i * 256;
      int n = f >> 3, k8 = (f & 7) << 3;
      uint4 v = *(const uint4*)(W1t + (size_t)n * IN_F + k0 + k8);
      int byte = n * 128 + (k8 << 1);
      byte ^= (n & 7) << 4;
      *(uint4*)(Ws + byte) = v;
    }
    __syncthreads();
    #pragma unroll
    for (int ks = 0; ks < 64; ks += 32) {
      int kk = ks + (lhi << 3);
      int ba = rA * 128 + (kk << 1); ba ^= (rA & 7) << 4;
      short8 a = *(const short8*)(As + ba);
      #pragma unroll
      for (int j = 0; j < 4; ++j) {
        int nB = (j << 4) + l15;
        int bb = nB * 128 + (kk << 1); bb ^= (nB & 7) << 4;
        short8 bv = *(const short8*)(Ws + bb);
        acc[j] = __builtin_amdgcn_mfma_f32_16x16x32_bf16(a, bv, acc[j], 0, 0, 0);
      }
    }
    __syncthreads();
  }
  int rbase = row0 + (wave << 4) + (lhi << 2);
  #pragma unroll
  for (int r = 0; r < 4; ++r) {
    int gr = rbase + r;
    if (gr < N_NODES) {
      float dn = dinv[gr];
      #pragma unroll
      for (int j = 0; j < 4; ++j)
        h0q[((size_t)j * N_NODES + gr) * 16 + l15] = f2bf(dn * acc[j][r]);
    }
  }
}

// ---------- unified 16-feature aggregation pass ----------
// one wave/node, 8 groups x 8 lanes, 2 feats/lane (uint)
// out[node*ostride + f] = act(dinv*(self + sum_src hq[src]) + bias[f])
__global__ __launch_bounds__(256) void aggq_k(const unsigned* __restrict__ hq,
                                              const int* __restrict__ rowptr,
                                              const int* __restrict__ srcs,
                                              const float* __restrict__ dinv,
                                              const float* __restrict__ bias,
                                              float* __restrict__ out,
                                              int ostride, int do_relu) {
  int idx = blockIdx.x * 256 + threadIdx.x;
  int node = idx >> 6;
  if (node >= N_NODES) return;
  int lane = threadIdx.x & 63;
  int ln = lane & 7, g = lane >> 3;
  int p0 = rowptr[node], p1 = rowptr[node + 1];
  int c = p1 - p0;
  int ps = p0 + ((c * g) >> 3);
  int pe = p0 + ((c * (g + 1)) >> 3);
  float a0 = 0.f, a1 = 0.f;
  if (g == 0) {
    unsigned u = hq[(size_t)node * 8 + ln];   // self (pre-scaled)
    a0 = bf2f(u & 0xffffu); a1 = bf2f(u >> 16);
  }
  int p = ps;
  for (; p + 4 <= pe; p += 4) {
    int s0 = srcs[p], s1 = srcs[p + 1], s2 = srcs[p + 2], s3 = srcs[p + 3];
    unsigned u0 = hq[(size_t)s0 * 8 + ln];
    unsigned u1 = hq[(size_t)s1 * 8 + ln];
    unsigned u2 = hq[(size_t)s2 * 8 + ln];
    unsigned u3 = hq[(size_t)s3 * 8 + ln];
    a0 += (bf2f(u0 & 0xffffu) + bf2f(u1 & 0xffffu)) + (bf2f(u2 & 0xffffu) + bf2f(u3 & 0xffffu));
    a1 += (bf2f(u0 >> 16) + bf2f(u1 >> 16)) + (bf2f(u2 >> 16) + bf2f(u3 >> 16));
  }
  for (; p < pe; ++p) {
    unsigned u = hq[(size_t)srcs[p] * 8 + ln];
    a0 += bf2f(u & 0xffffu); a1 += bf2f(u >> 16);
  }
  #pragma unroll
  for (int off = 8; off < 64; off <<= 1) {
    a0 += __shfl_xor(a0, off);
    a1 += __shfl_xor(a1, off);
  }
  if (g == 0) {
    float dn = dinv[node];
    float2 st;
    st.x = dn * a0 + bias[ln * 2];
    st.y = dn * a1 + bias[ln * 2 + 1];
    if (do_relu) { st.x = fmaxf(st.x, 0.f); st.y = fmaxf(st.y, 0.f); }
    *(float2*)(out + (size_t)node * ostride + ln * 2) = st;
  }
}

// ---------- GEMM2: h2h[half][node][16] = bf16(dinv*(h@W2)) half-split ----------
__global__ __launch_bounds__(256) void gemm2_k(const float* __restrict__ h,
                                               const float* __restrict__ W2,
                                               const float* __restrict__ dinv,
                                               unsigned short* __restrict__ h2h) {
  __shared__ float w2s[HID * N_CLS];
  __shared__ float hs[32][HID];
  int tid = threadIdx.x;
  for (int i = tid; i < HID * N_CLS; i += 256) w2s[i] = W2[i];
  int node0 = blockIdx.x * 32;
  for (int i = tid; i < 32 * HID / 4; i += 256) {
    int r = i >> 4, c4 = (i & 15) << 2;
    int g = node0 + r;
    float4 v = make_float4(0.f, 0.f, 0.f, 0.f);
    if (g < N_NODES) v = *(const float4*)(h + (size_t)g * HID + c4);
    *(float4*)&hs[r][c4] = v;
  }
  __syncthreads();
  int cls = tid & 31, nl = tid >> 5;
  int half = cls >> 4, cl = cls & 15;
  float acc[4] = {0.f, 0.f, 0.f, 0.f};
  #pragma unroll
  for (int k = 0; k < HID; ++k) {
    float w = w2s[k * N_CLS + cls];
    #pragma unroll
    for (int j = 0; j < 4; ++j) acc[j] += hs[nl * 4 + j][k] * w;
  }
  #pragma unroll
  for (int j = 0; j < 4; ++j) {
    int g = node0 + nl * 4 + j;
    if (g < N_NODES) h2h[((size_t)half * N_NODES + g) * 16 + cl] = f2bf(dinv[g] * acc[j]);
  }
}

extern "C" void kernel_launch(void* const* d_in, const int* in_sizes, int n_in,
                              void* d_out, int out_size, void* d_ws, size_t ws_size,
                              hipStream_t stream) {
  const float* x  = (const float*)d_in[0];
  const int*   ei = (const int*)d_in[1];
  const float* W1 = (const float*)d_in[2];
  const float* b1 = (const float*)d_in[3];
  const float* W2 = (const float*)d_in[4];
  const float* b2 = (const float*)d_in[5];
  float* out_h = (float*)d_out;
  float* out_z = out_h + (size_t)N_NODES * HID;

  char* ws = (char*)d_ws;
  int* bcnt           = (int*)(ws + 0);                       // 1.6 KB
  int* bbase          = (int*)(ws + (4 << 10));               // 1.6 KB
  int* bcur           = (int*)(ws + (8 << 10));               // 1.6 KB
  int* rowptr         = (int*)(ws + (16 << 10));              // 400 KB + 4
  float* dinv         = (float*)(ws + (528 << 10));           // 400 KB
  unsigned short* W1t = (unsigned short*)(ws + (944 << 10));  // 64 KB
  unsigned* tmp       = (unsigned*)(ws + (1024 << 10));       // 6.4 MB
  int* srcs           = (int*)(ws + (8ull << 20));            // 6.4 MB
  unsigned short* h0q = (unsigned short*)(ws + (15ull << 20));// 12.8 MB (4 quarters)
  unsigned short* h2h = (unsigned short*)(ws + (28ull << 20));// 6.4 MB (2 halves)

  hipMemsetAsync(bcnt, 0, NBKT2 * sizeof(int), stream);
  w1t_k<<<(IN_F * HID + 255) / 256, 256, 0, stream>>>(W1, W1t);
  coarse_hist_k<<<NBLKA, 256, 0, stream>>>(ei, bcnt);
  coarse_scan_k<<<1, 512, 0, stream>>>(bcnt, bbase, bcur);
  passA_k<<<NBLKA, 256, 0, stream>>>(ei, bcur, tmp);
  passB_k<<<NBKT2, 256, 0, stream>>>(tmp, bbase, rowptr, dinv, srcs);
  gemm1_mfma_k<<<(N_NODES + 63) / 64, 256, 0, stream>>>(x, W1t, dinv, h0q);
  // layer 1 aggregation: 4 feature-quarter passes, each L2-resident (3.2 MB)
  for (int q = 0; q < 4; ++q)
    aggq_k<<<(N_NODES * 64) / 256, 256, 0, stream>>>(
        (const unsigned*)(h0q + (size_t)q * N_NODES * 16), rowptr, srcs, dinv,
        b1 + q * 16, out_h + q * 16, HID, 1);
  gemm2_k<<<(N_NODES + 31) / 32, 256, 0, stream>>>(out_h, W2, dinv, h2h);
  // layer 2 aggregation: 2 feature-half passes
  for (int q = 0; q < 2; ++q)
    aggq_k<<<(N_NODES * 64) / 256, 256, 0, stream>>>(
        (const unsigned*)(h2h + (size_t)q * N_NODES * 16), rowptr, srcs, dinv,
        b2 + q * 16, out_z + q * 16, N_CLS, 0);
}

// Round 8
// 217.194 us; speedup vs baseline: 5.3907x; 1.6975x over previous
//
#include <hip/hip_runtime.h>

#define N_NODES 100000
#define N_EDGES 1600000
#define IN_F 512
#define HID 64
#define N_CLS 32
#define NBKT2 391      // 256-node buckets: ceil(100000/256)
#define EBLK 8192      // edges per passA/coarse-hist block
#define NBLKA ((N_EDGES + EBLK - 1) / EBLK)   // 196

typedef __attribute__((ext_vector_type(8))) short short8;
typedef __attribute__((ext_vector_type(4))) float f32x4;

__device__ __forceinline__ unsigned short f2bf(float f) {
  unsigned int u = __float_as_uint(f);
  u += 0x7FFFu + ((u >> 16) & 1u);
  return (unsigned short)(u >> 16);
}
__device__ __forceinline__ float bf2f(unsigned int s) {
  return __uint_as_float(s << 16);
}

// ---------- W1 transpose to bf16 (+ zero bcnt for the next kernel) ----------
__global__ __launch_bounds__(256) void w1t_k(const float* __restrict__ W1,
                                             unsigned short* __restrict__ W1t,
                                             int* __restrict__ bcnt) {
  int i = blockIdx.x * 256 + threadIdx.x;
  if (i < NBKT2) bcnt[i] = 0;
  if (i < IN_F * HID) {
    int n = i >> 9, k = i & 511;
    W1t[i] = f2bf(W1[(size_t)k * HID + n]);
  }
}

// ---------- coarse histogram over 391 buckets; saves per-block rows ----------
__global__ __launch_bounds__(256) void coarse_hist_k(const int* __restrict__ ei,
                                                     int* __restrict__ bcnt,
                                                     int* __restrict__ bhist) {
  __shared__ int lh[NBKT2];
  int tid = threadIdx.x;
  for (int b = tid; b < NBKT2; b += 256) lh[b] = 0;
  __syncthreads();
  int e0 = blockIdx.x * EBLK;
  int e1 = min(e0 + EBLK, N_EDGES);
  for (int e = e0 + tid; e < e1; e += 256)
    atomicAdd(&lh[ei[N_EDGES + e] >> 8], 1);
  __syncthreads();
  for (int b = tid; b < NBKT2; b += 256) {
    int c = lh[b];
    bhist[blockIdx.x * NBKT2 + b] = c;
    if (c) atomicAdd(&bcnt[b], c);
  }
}

// ---------- single-block scan of 391 bucket counts ----------
__global__ __launch_bounds__(512) void coarse_scan_k(const int* __restrict__ bcnt,
                                                     int* __restrict__ bbase,
                                                     int* __restrict__ bcur) {
  __shared__ int sc[512];
  int tid = threadIdx.x;
  int v = (tid < NBKT2) ? bcnt[tid] : 0;
  sc[tid] = v;
  __syncthreads();
  for (int off = 1; off < 512; off <<= 1) {
    int t = (tid >= off) ? sc[tid - off] : 0;
    __syncthreads();
    sc[tid] += t;
    __syncthreads();
  }
  int incl = sc[tid];
  int excl = incl - v;
  if (tid < NBKT2) { bbase[tid] = excl; bcur[tid] = excl; }
  if (tid == NBKT2 - 1) bbase[NBKT2] = incl;   // == N_EDGES
}

// ---------- pass A: block-private run reservation (uses precomputed bhist) ----------
__global__ __launch_bounds__(256) void passA_k(const int* __restrict__ ei,
                                               const int* __restrict__ bhist,
                                               int* __restrict__ bcur,
                                               unsigned* __restrict__ tmp) {
  __shared__ int gcur[NBKT2];
  int tid = threadIdx.x;
  int e0 = blockIdx.x * EBLK;
  int e1 = min(e0 + EBLK, N_EDGES);
  for (int b = tid; b < NBKT2; b += 256) {
    int c = bhist[blockIdx.x * NBKT2 + b];
    gcur[b] = c ? atomicAdd(&bcur[b], c) : 0;
  }
  __syncthreads();
  for (int e = e0 + tid; e < e1; e += 256) {
    int s = ei[e], d = ei[N_EDGES + e];
    int p = atomicAdd(&gcur[d >> 8], 1);
    tmp[p] = ((unsigned)s << 8) | (unsigned)(d & 255);
  }
}

// ---------- pass B: per-bucket node hist + scan + rowptr/dinv + exact placement ----------
__global__ __launch_bounds__(256) void passB_k(const unsigned* __restrict__ tmp,
                                               const int* __restrict__ bbase,
                                               int* __restrict__ rowptr,
                                               float* __restrict__ dinv,
                                               int* __restrict__ srcs) {
  __shared__ int sc[256];
  __shared__ int cur[256];
  int b = blockIdx.x, tid = threadIdx.x;
  int n0 = b << 8;
  int n1 = min(n0 + 256, N_NODES);
  int base = bbase[b], end = bbase[b + 1];
  sc[tid] = 0;
  __syncthreads();
  for (int i = base + tid; i < end; i += 256)
    atomicAdd(&sc[tmp[i] & 255u], 1);
  __syncthreads();
  int myc = sc[tid];
  for (int off = 1; off < 256; off <<= 1) {
    int t = (tid >= off) ? sc[tid - off] : 0;
    __syncthreads();
    sc[tid] += t;
    __syncthreads();
  }
  int incl = sc[tid];
  int excl = incl - myc;
  if (n0 + tid < n1) {
    rowptr[n0 + tid + 1] = base + incl;
    dinv[n0 + tid] = rsqrtf((float)(myc + 1));
  }
  if (b == 0 && tid == 0) rowptr[0] = 0;
  cur[tid] = base + excl;
  __syncthreads();
  for (int i = base + tid; i < end; i += 256) {
    unsigned v = tmp[i];
    int p = atomicAdd(&cur[v & 255u], 1);
    srcs[p] = (int)(v >> 8);
  }
}

// ---------- GEMM1 (MFMA bf16): h0s = dinv * (x @ W1), bf16 [N][64] ----------
__global__ __launch_bounds__(256) void gemm1_mfma_k(const float* __restrict__ x,
                                                    const unsigned short* __restrict__ W1t,
                                                    const float* __restrict__ dinv,
                                                    unsigned short* __restrict__ h0s) {
  __shared__ __align__(16) char As[64 * 128];
  __shared__ __align__(16) char Ws[64 * 128];
  int tid = threadIdx.x;
  int wave = tid >> 6, lane = tid & 63;
  int row0 = blockIdx.x * 64;
  f32x4 acc[4] = {{0.f,0.f,0.f,0.f},{0.f,0.f,0.f,0.f},{0.f,0.f,0.f,0.f},{0.f,0.f,0.f,0.f}};

  int l15 = lane & 15, lhi = lane >> 4;
  int rA = (wave << 4) + l15;

  for (int k0 = 0; k0 < IN_F; k0 += 64) {
    #pragma unroll
    for (int i = 0; i < 4; ++i) {
      int f = tid + i * 256;
      int r = f >> 4, c4 = (f & 15) << 2;
      float4 v = make_float4(0.f, 0.f, 0.f, 0.f);
      int gr = row0 + r;
      if (gr < N_NODES) v = *(const float4*)(x + (size_t)gr * IN_F + k0 + c4);
      ushort4 u;
      u.x = f2bf(v.x); u.y = f2bf(v.y); u.z = f2bf(v.z); u.w = f2bf(v.w);
      int byte = r * 128 + (c4 << 1);
      byte ^= (r & 7) << 4;
      *(ushort4*)(As + byte) = u;
    }
    #pragma unroll
    for (int i = 0; i < 2; ++i) {
      int f = tid + i * 256;
      int n = f >> 3, k8 = (f & 7) << 3;
      uint4 v = *(const uint4*)(W1t + (size_t)n * IN_F + k0 + k8);
      int byte = n * 128 + (k8 << 1);
      byte ^= (n & 7) << 4;
      *(uint4*)(Ws + byte) = v;
    }
    __syncthreads();
    #pragma unroll
    for (int ks = 0; ks < 64; ks += 32) {
      int kk = ks + (lhi << 3);
      int ba = rA * 128 + (kk << 1); ba ^= (rA & 7) << 4;
      short8 a = *(const short8*)(As + ba);
      #pragma unroll
      for (int j = 0; j < 4; ++j) {
        int nB = (j << 4) + l15;
        int bb = nB * 128 + (kk << 1); bb ^= (nB & 7) << 4;
        short8 bv = *(const short8*)(Ws + bb);
        acc[j] = __builtin_amdgcn_mfma_f32_16x16x32_bf16(a, bv, acc[j], 0, 0, 0);
      }
    }
    __syncthreads();
  }
  int rbase = row0 + (wave << 4) + (lhi << 2);
  #pragma unroll
  for (int r = 0; r < 4; ++r) {
    int gr = rbase + r;
    if (gr < N_NODES) {
      float dn = dinv[gr];
      #pragma unroll
      for (int j = 0; j < 4; ++j)
        h0s[(size_t)gr * HID + (j << 4) + l15] = f2bf(dn * acc[j][r]);
    }
  }
}

// ---------- agg1 + fused gemm2: one wave/node ----------
// h = relu(dinv*(self + sum) + b1) -> out_h (f32) and, in-wave, h2b = bf16(dinv*(h@W2))
__global__ __launch_bounds__(256) void agg1g2_k(const uint4* __restrict__ h0q,
                                                const int* __restrict__ rowptr,
                                                const int* __restrict__ srcs,
                                                const float* __restrict__ dinv,
                                                const float* __restrict__ b1,
                                                const float* __restrict__ W2,
                                                float* __restrict__ out_h,
                                                unsigned short* __restrict__ h2b) {
  __shared__ float w2s[HID * N_CLS];   // [k][cls], 8 KB
  __shared__ float hrow[4][HID];       // per-wave h row
  int tid = threadIdx.x;
  for (int i = tid; i < HID * N_CLS; i += 256) w2s[i] = W2[i];
  __syncthreads();

  int idx = blockIdx.x * 256 + tid;
  int node = idx >> 6;                  // grid sized so node < N_NODES always
  int wv = tid >> 6;
  int lane = tid & 63;
  int fl = lane & 7, g = lane >> 3;
  int p0 = rowptr[node], p1 = rowptr[node + 1];
  int c = p1 - p0;
  int ps = p0 + ((c * g) >> 3);
  int pe = p0 + ((c * (g + 1)) >> 3);
  float a[8] = {0.f,0.f,0.f,0.f,0.f,0.f,0.f,0.f};
  if (g == 0) {
    uint4 u = h0q[(size_t)node * 8 + fl];     // self (pre-scaled)
    a[0] = bf2f(u.x & 0xffffu); a[1] = bf2f(u.x >> 16);
    a[2] = bf2f(u.y & 0xffffu); a[3] = bf2f(u.y >> 16);
    a[4] = bf2f(u.z & 0xffffu); a[5] = bf2f(u.z >> 16);
    a[6] = bf2f(u.w & 0xffffu); a[7] = bf2f(u.w >> 16);
  }
  int p = ps;
  for (; p + 2 <= pe; p += 2) {
    int s0 = srcs[p], s1 = srcs[p + 1];
    uint4 u0 = h0q[(size_t)s0 * 8 + fl];
    uint4 u1 = h0q[(size_t)s1 * 8 + fl];
    a[0] += bf2f(u0.x & 0xffffu) + bf2f(u1.x & 0xffffu);
    a[1] += bf2f(u0.x >> 16)     + bf2f(u1.x >> 16);
    a[2] += bf2f(u0.y & 0xffffu) + bf2f(u1.y & 0xffffu);
    a[3] += bf2f(u0.y >> 16)     + bf2f(u1.y >> 16);
    a[4] += bf2f(u0.z & 0xffffu) + bf2f(u1.z & 0xffffu);
    a[5] += bf2f(u0.z >> 16)     + bf2f(u1.z >> 16);
    a[6] += bf2f(u0.w & 0xffffu) + bf2f(u1.w & 0xffffu);
    a[7] += bf2f(u0.w >> 16)     + bf2f(u1.w >> 16);
  }
  if (p < pe) {
    uint4 u = h0q[(size_t)srcs[p] * 8 + fl];
    a[0] += bf2f(u.x & 0xffffu); a[1] += bf2f(u.x >> 16);
    a[2] += bf2f(u.y & 0xffffu); a[3] += bf2f(u.y >> 16);
    a[4] += bf2f(u.z & 0xffffu); a[5] += bf2f(u.z >> 16);
    a[6] += bf2f(u.w & 0xffffu); a[7] += bf2f(u.w >> 16);
  }
  #pragma unroll
  for (int off = 8; off < 64; off <<= 1) {
    #pragma unroll
    for (int i = 0; i < 8; ++i) a[i] += __shfl_xor(a[i], off);
  }
  float dn = dinv[node];
  if (g == 0) {
    float4 bA = *(const float4*)(b1 + fl * 8);
    float4 bB = *(const float4*)(b1 + fl * 8 + 4);
    float4 s0, s1;
    s0.x = fmaxf(dn * a[0] + bA.x, 0.f); s0.y = fmaxf(dn * a[1] + bA.y, 0.f);
    s0.z = fmaxf(dn * a[2] + bA.z, 0.f); s0.w = fmaxf(dn * a[3] + bA.w, 0.f);
    s1.x = fmaxf(dn * a[4] + bB.x, 0.f); s1.y = fmaxf(dn * a[5] + bB.y, 0.f);
    s1.z = fmaxf(dn * a[6] + bB.z, 0.f); s1.w = fmaxf(dn * a[7] + bB.w, 0.f);
    *(float4*)(out_h + (size_t)node * HID + fl * 8) = s0;
    *(float4*)(out_h + (size_t)node * HID + fl * 8 + 4) = s1;
    *(float4*)&hrow[wv][fl * 8] = s0;
    *(float4*)&hrow[wv][fl * 8 + 4] = s1;
  }
  // same wave reads its own LDS writes (compiler inserts lgkmcnt wait)
  int cls = lane & 31, kb = (lane >> 5) << 5;   // k-half per lane pair
  float acc2 = 0.f;
  #pragma unroll
  for (int k = 0; k < 32; ++k)
    acc2 += hrow[wv][kb + k] * w2s[(kb + k) * N_CLS + cls];
  acc2 += __shfl_xor(acc2, 32);
  if (lane < 32)
    h2b[(size_t)node * N_CLS + cls] = f2bf(dn * acc2);
}

// ---------- agg2: one wave/node, 8-way edge split, 4 feats/lane (uint2) ----------
__global__ __launch_bounds__(256) void agg2_k(const uint2* __restrict__ h2u,
                                              const int* __restrict__ rowptr,
                                              const int* __restrict__ srcs,
                                              const float* __restrict__ dinv,
                                              const float* __restrict__ b2,
                                              float* __restrict__ out) {
  int idx = blockIdx.x * 256 + threadIdx.x;
  int node = idx >> 6;
  if (node >= N_NODES) return;
  int lane = threadIdx.x & 63;
  int fl = lane & 7, g = lane >> 3;
  int p0 = rowptr[node], p1 = rowptr[node + 1];
  int c = p1 - p0;
  int ps = p0 + ((c * g) >> 3);
  int pe = p0 + ((c * (g + 1)) >> 3);
  float a0 = 0.f, a1 = 0.f, a2 = 0.f, a3 = 0.f;
  if (g == 0) {
    uint2 u = h2u[(size_t)node * 8 + fl];
    a0 = bf2f(u.x & 0xffffu); a1 = bf2f(u.x >> 16);
    a2 = bf2f(u.y & 0xffffu); a3 = bf2f(u.y >> 16);
  }
  int p = ps;
  for (; p + 2 <= pe; p += 2) {
    int s0 = srcs[p], s1 = srcs[p + 1];
    uint2 u0 = h2u[(size_t)s0 * 8 + fl];
    uint2 u1 = h2u[(size_t)s1 * 8 + fl];
    a0 += bf2f(u0.x & 0xffffu) + bf2f(u1.x & 0xffffu);
    a1 += bf2f(u0.x >> 16)     + bf2f(u1.x >> 16);
    a2 += bf2f(u0.y & 0xffffu) + bf2f(u1.y & 0xffffu);
    a3 += bf2f(u0.y >> 16)     + bf2f(u1.y >> 16);
  }
  if (p < pe) {
    uint2 u = h2u[(size_t)srcs[p] * 8 + fl];
    a0 += bf2f(u.x & 0xffffu); a1 += bf2f(u.x >> 16);
    a2 += bf2f(u.y & 0xffffu); a3 += bf2f(u.y >> 16);
  }
  #pragma unroll
  for (int off = 8; off < 64; off <<= 1) {
    a0 += __shfl_xor(a0, off); a1 += __shfl_xor(a1, off);
    a2 += __shfl_xor(a2, off); a3 += __shfl_xor(a3, off);
  }
  if (g == 0) {
    float dn = dinv[node];
    float4 bv = *(const float4*)(b2 + fl * 4);
    float4 st;
    st.x = dn * a0 + bv.x; st.y = dn * a1 + bv.y;
    st.z = dn * a2 + bv.z; st.w = dn * a3 + bv.w;
    *(float4*)(out + (size_t)node * N_CLS + fl * 4) = st;
  }
}

extern "C" void kernel_launch(void* const* d_in, const int* in_sizes, int n_in,
                              void* d_out, int out_size, void* d_ws, size_t ws_size,
                              hipStream_t stream) {
  const float* x  = (const float*)d_in[0];
  const int*   ei = (const int*)d_in[1];
  const float* W1 = (const float*)d_in[2];
  const float* b1 = (const float*)d_in[3];
  const float* W2 = (const float*)d_in[4];
  const float* b2 = (const float*)d_in[5];
  float* out_h = (float*)d_out;
  float* out_z = out_h + (size_t)N_NODES * HID;

  char* ws = (char*)d_ws;
  int* bcnt           = (int*)(ws + 0);                       // 1.6 KB
  int* bbase          = (int*)(ws + (4 << 10));               // 1.6 KB
  int* bcur           = (int*)(ws + (8 << 10));               // 1.6 KB
  int* bhist          = (int*)(ws + (12 << 10));              // 306 KB
  int* rowptr         = (int*)(ws + (336 << 10));             // 400 KB + 4
  float* dinv         = (float*)(ws + (752 << 10));           // 400 KB
  unsigned short* W1t = (unsigned short*)(ws + (1168 << 10)); // 64 KB
  unsigned* tmp       = (unsigned*)(ws + (1280 << 10));       // 6.4 MB
  int* srcs           = (int*)(ws + (8ull << 20));            // 6.4 MB
  unsigned short* h0s = (unsigned short*)(ws + (15ull << 20));// 12.8 MB
  unsigned short* h2b = (unsigned short*)(ws + (28ull << 20));// 6.4 MB

  w1t_k<<<(IN_F * HID + 255) / 256, 256, 0, stream>>>(W1, W1t, bcnt);
  coarse_hist_k<<<NBLKA, 256, 0, stream>>>(ei, bcnt, bhist);
  coarse_scan_k<<<1, 512, 0, stream>>>(bcnt, bbase, bcur);
  passA_k<<<NBLKA, 256, 0, stream>>>(ei, bhist, bcur, tmp);
  passB_k<<<NBKT2, 256, 0, stream>>>(tmp, bbase, rowptr, dinv, srcs);
  gemm1_mfma_k<<<(N_NODES + 63) / 64, 256, 0, stream>>>(x, W1t, dinv, h0s);
  agg1g2_k<<<(N_NODES * 64) / 256, 256, 0, stream>>>((const uint4*)h0s, rowptr, srcs,
                                                     dinv, b1, W2, out_h, h2b);
  agg2_k<<<(N_NODES * 64) / 256, 256, 0, stream>>>((const uint2*)h2b, rowptr, srcs,
                                                   dinv, b2, out_z);
}